// Round 5
// baseline (105.292 us; speedup 1.0000x reference)
//
#include <hip/hip_runtime.h>

// SoftMinLayer via MFMA, two-phase softmin (R5 = R3 numerics + structural ILP).
// Phase 1: hi*hi MFMA only -> approximate per-k min reference (mqa). No exps.
// Phase 2: full 3-term bf16 hi/lo MFMA in TWO nt-group sub-passes (B-lo hoisted
//          to registers per group; two independent 3-MFMA accumulator chains);
//          branchless w = exp2f(t*CQ), t = q - mqa; track tmin;
//          out = (T/S - tmin) / L   (shift-exact, identical math to R3-pass).
// q = sqw - 2*cross (ssq cancels in D - minD). 512 thr / 8 waves.
// LDS 64.7 KB -> 2 blocks/CU; launch_bounds(512,2) => 128-VGPR cap
// (2nd arg = min blocks/CU on this stack; (512,4) = 64-VGPR cap = spill disaster).

#define N_SEQ   512
#define Q_LEN   1024
#define K_SH    100
#define L_SH    50
#define J_WIN   974              // Q - L
#define NTILE   7                // ceil(100/16) k-tiles
#define MTILES  61               // ceil(974/16) j-tiles (976 rows incl 2 pad)
#define NWAVE   8
#define RINV_L  0.02f            // 1/50
#define PAD_SQ  4e31f            // sq_win pad -> w = exp2f(-1.15e32) = 0 exactly
#define CQ      (-2.8853900817779268f)   // ALPHA * log2(e) / L = -2*log2(e)

#define CPR     1064             // region stride (elems) for shifted copies
#define BLSTR   120              // bl_lds lane stride (shorts; 240B, 16B-aligned)

typedef short  short8 __attribute__((ext_vector_type(8)));
typedef float  f32x4  __attribute__((ext_vector_type(4)));
typedef unsigned int uintx4 __attribute__((ext_vector_type(4)));

union V8 { short8 s; uintx4 u; };

__device__ __forceinline__ unsigned int bf16h(float f) {
    unsigned int b = __float_as_uint(f);
    return (b + 0x7FFFu + ((b >> 16) & 1u)) >> 16;   // RNE to bf16 (finite inputs)
}
__device__ __forceinline__ float bf16back(unsigned int h) {
    return __uint_as_float(h << 16);
}

// Phase-2 sub-pass over nt in [NT0, NT0+NG): B-lo group register-resident,
// two independent 3-MFMA chains; R3's exact q-unit math; per-group reduce+stash.
#define PHASE2_GROUP(NT0, NG)                                                  \
  {                                                                            \
    short8 blg[NG][2];                                                         \
    float  mqg[NG];                                                            \
    _Pragma("unroll")                                                          \
    for (int nn = 0; nn < NG; ++nn) {                                          \
      blg[nn][0] = *(const short8*)&bl_lds[lane*BLSTR + (NT0+nn)*16];          \
      blg[nn][1] = *(const short8*)&bl_lds[lane*BLSTR + (NT0+nn)*16 + 8];      \
      mqg[nn]    = gm[(NT0+nn)*16 + bcol];                                     \
    }                                                                          \
    float Sg[NG], Tg[NG], tmg[NG];                                             \
    _Pragma("unroll")                                                          \
    for (int nn = 0; nn < NG; ++nn) { Sg[nn]=0.f; Tg[nn]=0.f; tmg[nn]=1e30f; } \
    for (int mt = w; mt < MTILES; mt += NWAVE) {                               \
      const int j0 = mt << 4;                                                  \
      const int ae = abase0 + j0;                                              \
      const short8 ah0 = *(const short8*)&cp[ae];                              \
      const short8 ah1 = *(const short8*)&cp[ae + 32];                         \
      const short8 al0 = *(const short8*)&cp[ae + CPR];                        \
      const short8 al1 = *(const short8*)&cp[ae + CPR + 32];                   \
      const float4 sqv = *(const float4*)&lds_sqw[j0 + 4*g];                   \
      _Pragma("unroll")                                                        \
      for (int nn = 0; nn < NG; ++nn) {                                        \
        f32x4 a0 = {0.f,0.f,0.f,0.f}, a1 = {0.f,0.f,0.f,0.f};                  \
        a0 = __builtin_amdgcn_mfma_f32_16x16x32_bf16(ah0, bh[NT0+nn][0], a0,0,0,0); \
        a1 = __builtin_amdgcn_mfma_f32_16x16x32_bf16(ah1, bh[NT0+nn][1], a1,0,0,0); \
        a0 = __builtin_amdgcn_mfma_f32_16x16x32_bf16(al0, bh[NT0+nn][0], a0,0,0,0); \
        a1 = __builtin_amdgcn_mfma_f32_16x16x32_bf16(al1, bh[NT0+nn][1], a1,0,0,0); \
        a0 = __builtin_amdgcn_mfma_f32_16x16x32_bf16(ah0, blg[nn][0],    a0,0,0,0); \
        a1 = __builtin_amdgcn_mfma_f32_16x16x32_bf16(ah1, blg[nn][1],    a1,0,0,0); \
        const float mq = mqg[nn];                                              \
        const float t0 = fmaf(a0[0], -2.f, fmaf(a1[0], -2.f, sqv.x - mq));     \
        const float t1 = fmaf(a0[1], -2.f, fmaf(a1[1], -2.f, sqv.y - mq));     \
        const float t2 = fmaf(a0[2], -2.f, fmaf(a1[2], -2.f, sqv.z - mq));     \
        const float t3 = fmaf(a0[3], -2.f, fmaf(a1[3], -2.f, sqv.w - mq));     \
        tmg[nn] = fminf(tmg[nn], fminf(fminf(t0, t1), fminf(t2, t3)));         \
        const float w0 = exp2f(t0 * CQ);                                       \
        const float w1 = exp2f(t1 * CQ);                                       \
        const float w2 = exp2f(t2 * CQ);                                       \
        const float w3 = exp2f(t3 * CQ);                                       \
        Sg[nn] += (w0 + w1) + (w2 + w3);                                       \
        float tv = Tg[nn];                                                     \
        tv = fmaf(t0, w0, tv);                                                 \
        tv = fmaf(t1, w1, tv);                                                 \
        tv = fmaf(t2, w2, tv);                                                 \
        tv = fmaf(t3, w3, tv);                                                 \
        Tg[nn] = tv;                                                           \
      }                                                                        \
    }                                                                          \
    _Pragma("unroll")                                                          \
    for (int nn = 0; nn < NG; ++nn) {                                          \
      float a = tmg[nn], s = Sg[nn], t = Tg[nn];                               \
      a = fminf(a, __shfl_xor(a, 16)); a = fminf(a, __shfl_xor(a, 32));        \
      s += __shfl_xor(s, 16); s += __shfl_xor(s, 32);                          \
      t += __shfl_xor(t, 16); t += __shfl_xor(t, 32);                          \
      if (lane < 16) {                                                         \
        const int idx = (w * NTILE + (NT0+nn)) * 16 + lane;                    \
        wred[idx] = a; redS[idx] = s; redT[idx] = t;                           \
      }                                                                        \
    }                                                                          \
  }

__global__ __launch_bounds__(512, 2)
void softmin_mfma_kernel(const float* __restrict__ x,
                         const float* __restrict__ sh,
                         float* __restrict__ out) {
    // 16 regions (r=0..7 x half=hi/lo) of CPR shorts: cp[(2r+half)*CPR + e] = x_half[e + r]
    __shared__ __align__(16) short cp[16 * CPR];          // 34,048 B
    __shared__ __align__(16) float lds_xf[1056];          //  4,224 B ; wred+gm overlay after prep
    __shared__ __align__(16) float lds_sqw[984];          //  3,936 B (974.. = PAD_SQ)
    __shared__ __align__(16) short bl_lds[64 * BLSTR];    // 15,360 B [lane][nt*16+ks*8]
    __shared__ __align__(16) float redS[NWAVE * 112];     //  3,584 B
    __shared__ __align__(16) float redT[NWAVE * 112];     //  3,584 B
    // total 64,736 B -> 2 blocks/CU

    const int i    = blockIdx.x;
    const int tid  = threadIdx.x;
    const int lane = tid & 63;
    const int w    = tid >> 6;     // wave 0..7
    const int g    = lane >> 4;    // 0..3
    const int bcol = lane & 15;

    // ---- B prep: load shapelets, pack bf16 hi/lo fragments ----
    // B[kappa][n] frag: lane holds kappa = l0 + 8g + i (i=0..7), n = nt*16 + bcol.
    short8 bh[NTILE][2];
    #pragma unroll
    for (int nt = 0; nt < NTILE; ++nt) {
        const int n = nt * 16 + bcol;
        float sv[16];
        #pragma unroll
        for (int e = 0; e < 16; ++e) sv[e] = 0.f;
        if (n < K_SH) {
            const float* srow = sh + n * L_SH;
            const float2* p0 = (const float2*)(srow + 8 * g);        // kappa 8g..8g+7 (<32)
            #pragma unroll
            for (int q = 0; q < 4; ++q) { float2 v = p0[q]; sv[2*q] = v.x; sv[2*q+1] = v.y; }
            if (g < 2) {                                             // kappa 32+8g..+7 (<48)
                const float2* p1 = (const float2*)(srow + 32 + 8 * g);
                #pragma unroll
                for (int q = 0; q < 4; ++q) { float2 v = p1[q]; sv[8+2*q] = v.x; sv[9+2*q] = v.y; }
            } else if (g == 2) {                                     // kappa 48,49 real
                float2 v = *(const float2*)(srow + 48);
                sv[8] = v.x; sv[9] = v.y;
            }                                                        // g==3: all >=50 -> 0
        }
        unsigned int hb[16];
        #pragma unroll
        for (int e = 0; e < 16; ++e) hb[e] = bf16h(sv[e]);
        V8 h0, h1;
        h0.u = uintx4{hb[0]|(hb[1]<<16),  hb[2]|(hb[3]<<16),  hb[4]|(hb[5]<<16),  hb[6]|(hb[7]<<16)};
        h1.u = uintx4{hb[8]|(hb[9]<<16),  hb[10]|(hb[11]<<16),hb[12]|(hb[13]<<16),hb[14]|(hb[15]<<16)};
        bh[nt][0] = h0.s; bh[nt][1] = h1.s;

        if (tid < 64) {   // lo frags are lane-determined: wave 0 writes for all
            unsigned int lb[16];
            #pragma unroll
            for (int e = 0; e < 16; ++e) lb[e] = bf16h(sv[e] - bf16back(hb[e]));
            *(uintx4*)&bl_lds[lane*BLSTR + nt*16] =
                uintx4{lb[0]|(lb[1]<<16),  lb[2]|(lb[3]<<16),  lb[4]|(lb[5]<<16),  lb[6]|(lb[7]<<16)};
            *(uintx4*)&bl_lds[lane*BLSTR + nt*16 + 8] =
                uintx4{lb[8]|(lb[9]<<16),  lb[10]|(lb[11]<<16),lb[12]|(lb[13]<<16),lb[14]|(lb[15]<<16)};
        }
    }

    // ---- stage x row (f32) into LDS, zero-pad to 1056 ----
    {
        const float4* gx = (const float4*)(x + (size_t)i * Q_LEN);
        float4* lx = (float4*)lds_xf;
        if (tid < 256) lx[tid] = gx[tid];
        if (tid < 8)   lx[256 + tid] = make_float4(0.f, 0.f, 0.f, 0.f);
    }
    __syncthreads();

    // ---- sq_win (exact fp32, sliding within groups of 4) ----
    if (tid < 246) {
        const float4* xf4 = (const float4*)lds_xf;
        float r0, r1, r2, r3;
        if (tid < 244) {
            float v[56];
            #pragma unroll
            for (int q = 0; q < 14; ++q) {
                float4 a = xf4[tid + q];
                v[4*q] = a.x; v[4*q+1] = a.y; v[4*q+2] = a.z; v[4*q+3] = a.w;
            }
            float s0 = 0.f;
            #pragma unroll
            for (int l = 0; l < L_SH; ++l) s0 = fmaf(v[l], v[l], s0);
            float s1 = fmaf(v[50], v[50], s0 - v[0]*v[0]);
            float s2 = fmaf(v[51], v[51], s1 - v[1]*v[1]);
            float s3 = fmaf(v[52], v[52], s2 - v[2]*v[2]);
            r0 = s0; r1 = s1; r2 = s2; r3 = s3;
            if (4*tid + 2 >= J_WIN) r2 = PAD_SQ;            // j = 974
            if (4*tid + 3 >= J_WIN) r3 = PAD_SQ;            // j = 975
        } else {
            r0 = r1 = r2 = r3 = PAD_SQ;                     // j 976..983
        }
        *(float4*)&lds_sqw[4*tid] = make_float4(r0, r1, r2, r3);
    }

    // ---- base bf16 hi/lo arrays (copy r=0) ----
    if (tid < 132) {
        const float4* xf4 = (const float4*)lds_xf;
        float4 a = xf4[2*tid], b = xf4[2*tid + 1];
        float xv[8] = {a.x, a.y, a.z, a.w, b.x, b.y, b.z, b.w};
        unsigned int hh[8], rr[8];
        #pragma unroll
        for (int e = 0; e < 8; ++e) {
            hh[e] = bf16h(xv[e]);
            rr[e] = bf16h(xv[e] - bf16back(hh[e]));
        }
        *(uintx4*)&cp[8*tid] =
            uintx4{hh[0]|(hh[1]<<16), hh[2]|(hh[3]<<16), hh[4]|(hh[5]<<16), hh[6]|(hh[7]<<16)};
        *(uintx4*)&cp[CPR + 8*tid] =
            uintx4{rr[0]|(rr[1]<<16), rr[2]|(rr[3]<<16), rr[4]|(rr[5]<<16), rr[6]|(rr[7]<<16)};
    }
    __syncthreads();

    // ---- shifted copies r=1..7 via aligned reads + 16-bit funnel shifts ----
    if (tid < 262) {                                         // 131 blocks x 2 halves
        const int half = tid & 1, blk = tid >> 1;
        const uintx4 A  = *(const uintx4*)&cp[half*CPR + 8*blk];
        const uintx4 B4 = *(const uintx4*)&cp[half*CPR + 8*blk + 8];
        unsigned int s[8] = {A[0], A[1], A[2], A[3], B4[0], B4[1], B4[2], B4[3]};
        #pragma unroll
        for (int r = 1; r < 8; ++r) {
            const int p = r >> 1;
            unsigned int o[4];
            if ((r & 1) == 0) {
                #pragma unroll
                for (int e = 0; e < 4; ++e) o[e] = s[p + e];
            } else {
                #pragma unroll
                for (int e = 0; e < 4; ++e) o[e] = (s[p + e] >> 16) | (s[p + e + 1] << 16);
            }
            *(uintx4*)&cp[(2*r + half)*CPR + 8*blk] = uintx4{o[0], o[1], o[2], o[3]};
        }
    }
    __syncthreads();

    // A frag elem i <-> x[j0 + (lane&15) + l0 + 8g + i]; start == lane (mod 8)
    // -> copy r = lane&7 at 8-aligned elem (j0 + l0 + 8*((lane>>3)&1) + 8g).
    const int r7       = lane & 7;
    const int lane_off = 8 * ((lane >> 3) & 1) + 8 * g;
    const int abase0   = (2 * r7) * CPR + lane_off;

    // ================= PHASE 1: hi*hi approximate min (q-units) =================
    float mreg[NTILE];
    #pragma unroll
    for (int nt = 0; nt < NTILE; ++nt) mreg[nt] = 1e30f;

    for (int mt = w; mt < MTILES; mt += NWAVE) {
        const int j0 = mt << 4;
        const int ae = abase0 + j0;
        const short8 ah0 = *(const short8*)&cp[ae];
        const short8 ah1 = *(const short8*)&cp[ae + 32];
        const float4 sqv = *(const float4*)&lds_sqw[j0 + 4 * g];

        #pragma unroll
        for (int nt = 0; nt < NTILE; ++nt) {
            f32x4 a0 = {0.f, 0.f, 0.f, 0.f}, a1 = {0.f, 0.f, 0.f, 0.f};
            a0 = __builtin_amdgcn_mfma_f32_16x16x32_bf16(ah0, bh[nt][0], a0, 0, 0, 0);
            a1 = __builtin_amdgcn_mfma_f32_16x16x32_bf16(ah1, bh[nt][1], a1, 0, 0, 0);
            const float q0 = fmaf(a0[0], -2.f, fmaf(a1[0], -2.f, sqv.x));
            const float q1 = fmaf(a0[1], -2.f, fmaf(a1[1], -2.f, sqv.y));
            const float q2 = fmaf(a0[2], -2.f, fmaf(a1[2], -2.f, sqv.z));
            const float q3 = fmaf(a0[3], -2.f, fmaf(a1[3], -2.f, sqv.w));
            mreg[nt] = fminf(mreg[nt], fminf(fminf(q0, q1), fminf(q2, q3)));
        }
    }

    // reduce approx min: lanes (g-groups) -> waves -> gm[nt*16+k]
    float* wred = lds_xf;            // [8][7][16] = 896 floats (lds_xf dead after prep)
    float* gm   = lds_xf + 896;      // [7][16]   = 112 floats
    #pragma unroll
    for (int nt = 0; nt < NTILE; ++nt) {
        float mm = mreg[nt];
        mm = fminf(mm, __shfl_xor(mm, 16));
        mm = fminf(mm, __shfl_xor(mm, 32));
        if (lane < 16) wred[(w * NTILE + nt) * 16 + lane] = mm;
    }
    __syncthreads();
    if (tid < NTILE * 16) {
        float v = wred[tid];
        #pragma unroll
        for (int ww = 1; ww < NWAVE; ++ww) v = fminf(v, wred[ww * 112 + tid]);
        gm[tid] = v;
    }
    __syncthreads();

    // ================= PHASE 2: two nt-group sub-passes (R3 math) =================
    PHASE2_GROUP(0, 4)
    PHASE2_GROUP(4, 3)
    __syncthreads();

    // ---- cross-wave merge + write:  M = (T/S - tmin) / L ----
    if (tid < NTILE * 16) {
        float tmin = wred[tid], Sf = redS[tid], Tf = redT[tid];
        #pragma unroll
        for (int ww = 1; ww < NWAVE; ++ww) {
            tmin = fminf(tmin, wred[ww * 112 + tid]);
            Sf += redS[ww * 112 + tid];
            Tf += redT[ww * 112 + tid];
        }
        const int nt = tid >> 4, kk = tid & 15;
        const int k = nt * 16 + kk;
        if (k < K_SH) out[(size_t)i * K_SH + k] = (Tf / Sf - tmin) * RINV_L;
    }
}

extern "C" void kernel_launch(void* const* d_in, const int* in_sizes, int n_in,
                              void* d_out, int out_size, void* d_ws, size_t ws_size,
                              hipStream_t stream) {
    const float* x  = (const float*)d_in[0];   // (512, 1024) f32
    const float* sh = (const float*)d_in[1];   // (100, 50)  f32
    float* out = (float*)d_out;                // (512, 100) f32

    softmin_mfma_kernel<<<N_SEQ, 512, 0, stream>>>(x, sh, out);
}

// Round 7
// 94.396 us; speedup vs baseline: 1.1154x; 1.1154x over previous
//
#include <hip/hip_runtime.h>

// SoftMinLayer via MFMA — R7: k-split across waves (one k-tile per wave).
// Numerics are R5-VERBATIM (the only HW-proven MFMA scheme for this op):
//   pass 1: hi*hi MFMA -> approximate per-k min reference mqa (no exps)
//   pass 2: full 3-term bf16 hi/lo MFMA; w = exp2f(t*CQ), t = q - mqa;
//           track exact tmin; out = (T/S - tmin)/L  (shift-exact).
// Decomposition change only: 448 thr / 7 waves, wave w owns k-tile nt=w and
// loops ALL 61 j-tiles. B-frags live = 16 regs (was 56-112) -> target ~70
// total regs so 14 waves/CU actually reside (R1/R3/R5 stuck at ~19% occ:
// AGPR-parked operands, uncounted by VGPR_Count, capped residency at 2-3
// waves/SIMD). mqa and the final reduce are wave-local (shfl only): no
// reduction tables, no overlays, ZERO barriers after prep.
// LDS 42.2 KB; launch_bounds(448,2) (2nd arg = min blocks/CU empirically).

#define N_SEQ   512
#define Q_LEN   1024
#define K_SH    100
#define L_SH    50
#define J_WIN   974              // Q - L
#define NTILE   7                // k-tiles == waves
#define MTILES  61               // j-tiles (976 rows incl 2 pad)
#define RINV_L  0.02f            // 1/50
#define PAD_SQ  4e31f            // sq_win pad -> w = exp2f(-1.15e32) = 0 exactly
#define CQ      (-2.8853900817779268f)   // ALPHA * log2(e) / L = -2*log2(e)

#define CPR     1064             // region stride (elems) for shifted copies

typedef short  short8 __attribute__((ext_vector_type(8)));
typedef float  f32x4  __attribute__((ext_vector_type(4)));
typedef unsigned int uintx4 __attribute__((ext_vector_type(4)));

union V8 { short8 s; uintx4 u; };

__device__ __forceinline__ unsigned int bf16h(float f) {
    unsigned int b = __float_as_uint(f);
    return (b + 0x7FFFu + ((b >> 16) & 1u)) >> 16;   // RNE to bf16 (finite inputs)
}
__device__ __forceinline__ float bf16back(unsigned int h) {
    return __uint_as_float(h << 16);
}

__global__ __launch_bounds__(448, 2)
void softmin_mfma_kernel(const float* __restrict__ x,
                         const float* __restrict__ sh,
                         float* __restrict__ out) {
    // 16 regions (r=0..7 x half=hi/lo) of CPR shorts: cp[(2r+half)*CPR + e] = x_half[e + r]
    __shared__ __align__(16) short cp[16 * CPR];          // 34,048 B
    __shared__ __align__(16) float lds_xf[1056];          //  4,224 B
    __shared__ __align__(16) float lds_sqw[984];          //  3,936 B (974.. = PAD_SQ)
    // total 42,208 B -> 2 blocks/CU (grid-limited)

    const int i    = blockIdx.x;
    const int tid  = threadIdx.x;
    const int lane = tid & 63;
    const int w    = tid >> 6;     // wave 0..6 == k-tile index nt
    const int g    = lane >> 4;    // 0..3
    const int bcol = lane & 15;

    // ---- B fragments for THIS wave's k-tile (nt = w), R5-verbatim values ----
    // B[kappa][n]: lane holds kappa = l0 + 8g + i (i=0..7), n = w*16 + bcol.
    short8 bh0, bh1, blo0, blo1;
    {
        const int n = w * 16 + bcol;
        float sv[16];
        #pragma unroll
        for (int e = 0; e < 16; ++e) sv[e] = 0.f;
        if (n < K_SH) {
            const float* srow = sh + n * L_SH;
            const float2* p0 = (const float2*)(srow + 8 * g);        // kappa 8g..8g+7 (<32)
            #pragma unroll
            for (int q = 0; q < 4; ++q) { float2 v = p0[q]; sv[2*q] = v.x; sv[2*q+1] = v.y; }
            if (g < 2) {                                             // kappa 32+8g..+7 (<48)
                const float2* p1 = (const float2*)(srow + 32 + 8 * g);
                #pragma unroll
                for (int q = 0; q < 4; ++q) { float2 v = p1[q]; sv[8+2*q] = v.x; sv[9+2*q] = v.y; }
            } else if (g == 2) {                                     // kappa 48,49 real
                float2 v = *(const float2*)(srow + 48);
                sv[8] = v.x; sv[9] = v.y;
            }                                                        // g==3 hi-half: all >=50 -> 0
        }
        unsigned int hb[16], lb[16];
        #pragma unroll
        for (int e = 0; e < 16; ++e) {
            hb[e] = bf16h(sv[e]);
            lb[e] = bf16h(sv[e] - bf16back(hb[e]));
        }
        V8 a, b, c, d;
        a.u = uintx4{hb[0]|(hb[1]<<16),  hb[2]|(hb[3]<<16),  hb[4]|(hb[5]<<16),  hb[6]|(hb[7]<<16)};
        b.u = uintx4{hb[8]|(hb[9]<<16),  hb[10]|(hb[11]<<16),hb[12]|(hb[13]<<16),hb[14]|(hb[15]<<16)};
        c.u = uintx4{lb[0]|(lb[1]<<16),  lb[2]|(lb[3]<<16),  lb[4]|(lb[5]<<16),  lb[6]|(lb[7]<<16)};
        d.u = uintx4{lb[8]|(lb[9]<<16),  lb[10]|(lb[11]<<16),lb[12]|(lb[13]<<16),lb[14]|(lb[15]<<16)};
        bh0 = a.s; bh1 = b.s; blo0 = c.s; blo1 = d.s;
    }

    // ---- stage x row (f32) into LDS, zero-pad to 1056 ----
    {
        const float4* gx = (const float4*)(x + (size_t)i * Q_LEN);
        float4* lx = (float4*)lds_xf;
        if (tid < 256) lx[tid] = gx[tid];
        if (tid < 8)   lx[256 + tid] = make_float4(0.f, 0.f, 0.f, 0.f);
    }
    __syncthreads();

    // ---- sq_win (exact fp32, sliding within groups of 4) ----
    if (tid < 246) {
        const float4* xf4 = (const float4*)lds_xf;
        float r0, r1, r2, r3;
        if (tid < 244) {
            float v[56];
            #pragma unroll
            for (int q = 0; q < 14; ++q) {
                float4 a = xf4[tid + q];
                v[4*q] = a.x; v[4*q+1] = a.y; v[4*q+2] = a.z; v[4*q+3] = a.w;
            }
            float s0 = 0.f;
            #pragma unroll
            for (int l = 0; l < L_SH; ++l) s0 = fmaf(v[l], v[l], s0);
            float s1 = fmaf(v[50], v[50], s0 - v[0]*v[0]);
            float s2 = fmaf(v[51], v[51], s1 - v[1]*v[1]);
            float s3 = fmaf(v[52], v[52], s2 - v[2]*v[2]);
            r0 = s0; r1 = s1; r2 = s2; r3 = s3;
            if (4*tid + 2 >= J_WIN) r2 = PAD_SQ;            // j = 974
            if (4*tid + 3 >= J_WIN) r3 = PAD_SQ;            // j = 975
        } else {
            r0 = r1 = r2 = r3 = PAD_SQ;                     // j 976..983
        }
        *(float4*)&lds_sqw[4*tid] = make_float4(r0, r1, r2, r3);
    }

    // ---- base bf16 hi/lo arrays (copy r=0) ----
    if (tid < 132) {
        const float4* xf4 = (const float4*)lds_xf;
        float4 a = xf4[2*tid], b = xf4[2*tid + 1];
        float xv[8] = {a.x, a.y, a.z, a.w, b.x, b.y, b.z, b.w};
        unsigned int hh[8], rr[8];
        #pragma unroll
        for (int e = 0; e < 8; ++e) {
            hh[e] = bf16h(xv[e]);
            rr[e] = bf16h(xv[e] - bf16back(hh[e]));
        }
        *(uintx4*)&cp[8*tid] =
            uintx4{hh[0]|(hh[1]<<16), hh[2]|(hh[3]<<16), hh[4]|(hh[5]<<16), hh[6]|(hh[7]<<16)};
        *(uintx4*)&cp[CPR + 8*tid] =
            uintx4{rr[0]|(rr[1]<<16), rr[2]|(rr[3]<<16), rr[4]|(rr[5]<<16), rr[6]|(rr[7]<<16)};
    }
    __syncthreads();

    // ---- shifted copies r=1..7 via aligned reads + 16-bit funnel shifts ----
    if (tid < 262) {                                         // 131 blocks x 2 halves
        const int half = tid & 1, blk = tid >> 1;
        const uintx4 A  = *(const uintx4*)&cp[half*CPR + 8*blk];
        const uintx4 B4 = *(const uintx4*)&cp[half*CPR + 8*blk + 8];
        unsigned int s[8] = {A[0], A[1], A[2], A[3], B4[0], B4[1], B4[2], B4[3]};
        #pragma unroll
        for (int r = 1; r < 8; ++r) {
            const int p = r >> 1;
            unsigned int o[4];
            if ((r & 1) == 0) {
                #pragma unroll
                for (int e = 0; e < 4; ++e) o[e] = s[p + e];
            } else {
                #pragma unroll
                for (int e = 0; e < 4; ++e) o[e] = (s[p + e] >> 16) | (s[p + e + 1] << 16);
            }
            *(uintx4*)&cp[(2*r + half)*CPR + 8*blk] = uintx4{o[0], o[1], o[2], o[3]};
        }
    }
    __syncthreads();
    // No barriers below this point: each wave is fully independent.

    // A frag elem i <-> x[j0 + (lane&15) + l0 + 8g + i]; start == lane (mod 8)
    // -> copy r = lane&7 at 8-aligned elem (j0 + l0 + 8*((lane>>3)&1) + 8g).
    const int r7       = lane & 7;
    const int lane_off = 8 * ((lane >> 3) & 1) + 8 * g;
    const int abase0   = (2 * r7) * CPR + lane_off;

    // ======== PASS 1: hi*hi approximate min over ALL j-tiles (q-units) ========
    float mreg = 1e30f;
    for (int mt = 0; mt < MTILES; ++mt) {
        const int j0 = mt << 4;
        const int ae = abase0 + j0;
        const short8 ah0 = *(const short8*)&cp[ae];
        const short8 ah1 = *(const short8*)&cp[ae + 32];
        const float4 sqv = *(const float4*)&lds_sqw[j0 + 4 * g];

        f32x4 a0 = {0.f, 0.f, 0.f, 0.f}, a1 = {0.f, 0.f, 0.f, 0.f};
        a0 = __builtin_amdgcn_mfma_f32_16x16x32_bf16(ah0, bh0, a0, 0, 0, 0);
        a1 = __builtin_amdgcn_mfma_f32_16x16x32_bf16(ah1, bh1, a1, 0, 0, 0);
        const float q0 = fmaf(a0[0], -2.f, fmaf(a1[0], -2.f, sqv.x));
        const float q1 = fmaf(a0[1], -2.f, fmaf(a1[1], -2.f, sqv.y));
        const float q2 = fmaf(a0[2], -2.f, fmaf(a1[2], -2.f, sqv.z));
        const float q3 = fmaf(a0[3], -2.f, fmaf(a1[3], -2.f, sqv.w));
        mreg = fminf(mreg, fminf(fminf(q0, q1), fminf(q2, q3)));
    }
    // wave-local reference min for this k-column (4 g-groups partition all j)
    mreg = fminf(mreg, __shfl_xor(mreg, 16));
    mreg = fminf(mreg, __shfl_xor(mreg, 32));
    const float mq = mreg;

    // ======== PASS 2: full 6-MFMA GEMM + branchless weights (R5 math) ========
    float S = 0.f, T = 0.f, tmin = 1e30f;
    for (int mt = 0; mt < MTILES; ++mt) {
        const int j0 = mt << 4;
        const int ae = abase0 + j0;
        const short8 ah0 = *(const short8*)&cp[ae];
        const short8 ah1 = *(const short8*)&cp[ae + 32];
        const short8 al0 = *(const short8*)&cp[ae + CPR];
        const short8 al1 = *(const short8*)&cp[ae + CPR + 32];
        const float4 sqv = *(const float4*)&lds_sqw[j0 + 4 * g];

        f32x4 a0 = {0.f, 0.f, 0.f, 0.f}, a1 = {0.f, 0.f, 0.f, 0.f};
        a0 = __builtin_amdgcn_mfma_f32_16x16x32_bf16(ah0, bh0,  a0, 0, 0, 0);
        a1 = __builtin_amdgcn_mfma_f32_16x16x32_bf16(ah1, bh1,  a1, 0, 0, 0);
        a0 = __builtin_amdgcn_mfma_f32_16x16x32_bf16(al0, bh0,  a0, 0, 0, 0);
        a1 = __builtin_amdgcn_mfma_f32_16x16x32_bf16(al1, bh1,  a1, 0, 0, 0);
        a0 = __builtin_amdgcn_mfma_f32_16x16x32_bf16(ah0, blo0, a0, 0, 0, 0);
        a1 = __builtin_amdgcn_mfma_f32_16x16x32_bf16(ah1, blo1, a1, 0, 0, 0);

        const float t0 = fmaf(a0[0], -2.f, fmaf(a1[0], -2.f, sqv.x - mq));
        const float t1 = fmaf(a0[1], -2.f, fmaf(a1[1], -2.f, sqv.y - mq));
        const float t2 = fmaf(a0[2], -2.f, fmaf(a1[2], -2.f, sqv.z - mq));
        const float t3 = fmaf(a0[3], -2.f, fmaf(a1[3], -2.f, sqv.w - mq));
        tmin = fminf(tmin, fminf(fminf(t0, t1), fminf(t2, t3)));

        const float w0 = exp2f(t0 * CQ);
        const float w1 = exp2f(t1 * CQ);
        const float w2 = exp2f(t2 * CQ);
        const float w3 = exp2f(t3 * CQ);
        S += (w0 + w1) + (w2 + w3);
        float tv = T;
        tv = fmaf(t0, w0, tv);
        tv = fmaf(t1, w1, tv);
        tv = fmaf(t2, w2, tv);
        tv = fmaf(t3, w3, tv);
        T = tv;
    }

    // ---- wave-local reduce (all lanes share mq -> plain sums) + write ----
    tmin = fminf(tmin, __shfl_xor(tmin, 16));
    tmin = fminf(tmin, __shfl_xor(tmin, 32));
    S += __shfl_xor(S, 16);  S += __shfl_xor(S, 32);
    T += __shfl_xor(T, 16);  T += __shfl_xor(T, 32);

    if (lane < 16) {
        const int k = w * 16 + lane;       // bcol == lane here
        if (k < K_SH) out[(size_t)i * K_SH + k] = (T / S - tmin) * RINV_L;
    }
}

extern "C" void kernel_launch(void* const* d_in, const int* in_sizes, int n_in,
                              void* d_out, int out_size, void* d_ws, size_t ws_size,
                              hipStream_t stream) {
    const float* x  = (const float*)d_in[0];   // (512, 1024) f32
    const float* sh = (const float*)d_in[1];   // (100, 50)  f32
    float* out = (float*)d_out;                // (512, 100) f32

    softmin_mfma_kernel<<<N_SEQ, 448, 0, stream>>>(x, sh, out);
}